// Round 7
// baseline (195.701 us; speedup 1.0000x reference)
//
#include <hip/hip_runtime.h>

// GraphSAGE fused forward — live path only (neighbors_2/W1 are dead code).
// INSTRUMENTATION ROUND: body identical to round-6 (known-correct), wrapped in
// an idempotent REPS=4 loop so (a) dur_us delta vs 122.6 measures the kernel,
// (b) the 4x dispatch exceeds the ~43us fill threshold and gets a rocprof
// counter row (VALUBusy / conflicts / occupancy / FETCH) for diagnosis.
// asm keep-alives prevent cross-rep CSE; trailing barrier prevents rep N+1
// LDS writes racing rep N output-phase reads.
//
//   d_in[0] nodes        int32 [4096]
//   d_in[1] neighbors_1  int32 [4096,16]
//   d_in[2] neighbors_2  (UNUSED)
//   d_in[3] node_features f32  [100000,128]
//   d_in[4] W1           (UNUSED)
//   d_in[5] W2           f32   [128,256]
//   d_in[6] Wo           f32   [64,128]
// out: softmax(relu(cat[feat, mean_nbr] @ W2^T) @ Wo^T)  f32 [4096,64]

constexpr int D = 128;
constexpr int H = 128;
constexpr int O = 64;
constexpr int S = 16;
constexpr int NB = 4096;
constexpr int SPB = 8;     // 512 blocks, 2 blocks/CU
constexpr int KP  = 32;    // W2 k-panel width
constexpr int REPS = 4;    // instrumentation multiplier (remove next round)

__global__ __launch_bounds__(256, 2) void sage_fused(
    const int* __restrict__ nodes,
    const int* __restrict__ neigh,
    const float* __restrict__ nf,
    const float* __restrict__ W2,
    const float* __restrict__ Wo,
    float* __restrict__ out)
{
    __shared__ float catl[SPB][2 * D];   //  8 KB  [origin | mean]
    __shared__ float w2l[2][H][KP];      // 32 KB  XOR quad-swizzled, dbuf
    __shared__ float wol[O][D];          // 32 KB  XOR quad-swizzled
    __shared__ float hl[SPB][H];         //  4 KB             total 76 KB

    const int t  = threadIdx.x;
    const int s0 = blockIdx.x * SPB;

    #pragma unroll 1
    for (int rep = 0; rep < REPS; ++rep) {

    // ---- issue W2 panel-0 loads first (coalesced 128B row segments) ----
    float4 pv[4];
    #pragma unroll
    for (int i = 0; i < 4; ++i) {
        const int idx = t + i * 256, row = idx >> 3, c4 = idx & 7;
        pv[i] = *reinterpret_cast<const float4*>(W2 + (size_t)row * (2 * D) + c4 * 4);
    }

    // ---- gather: wave w owns seeds 2w, 2w+1; lanes split 2x32 nbr halves ----
    {
        const int lane = t & 63;
        const int wv_  = t >> 6;
        const int d4   = lane & 31;
        const int sub  = lane >> 5;
        const float4* nf4 = reinterpret_cast<const float4*>(nf);

        int ids[2][8];
        #pragma unroll
        for (int si = 0; si < 2; ++si) {
            const int4* nbp = reinterpret_cast<const int4*>(
                neigh + (size_t)(s0 + 2 * wv_ + si) * S + sub * 8);
            const int4 a = nbp[0], b = nbp[1];
            ids[si][0] = a.x; ids[si][1] = a.y; ids[si][2] = a.z; ids[si][3] = a.w;
            ids[si][4] = b.x; ids[si][5] = b.y; ids[si][6] = b.z; ids[si][7] = b.w;
        }
        float4 sum[2] = {make_float4(0.f, 0.f, 0.f, 0.f),
                         make_float4(0.f, 0.f, 0.f, 0.f)};
        float4 orgv[2];
        #pragma unroll
        for (int si = 0; si < 2; ++si)
            orgv[si] = nf4[(size_t)nodes[s0 + 2 * wv_ + si] * (D / 4) + d4];
        #pragma unroll
        for (int k = 0; k < 8; ++k) {
            #pragma unroll
            for (int si = 0; si < 2; ++si) {
                const float4 v = nf4[(size_t)ids[si][k] * (D / 4) + d4];
                sum[si].x += v.x; sum[si].y += v.y;
                sum[si].z += v.z; sum[si].w += v.w;
            }
        }
        #pragma unroll
        for (int si = 0; si < 2; ++si) {
            float4 tot;
            tot.x = sum[si].x + __shfl_xor(sum[si].x, 32);
            tot.y = sum[si].y + __shfl_xor(sum[si].y, 32);
            tot.z = sum[si].z + __shfl_xor(sum[si].z, 32);
            tot.w = sum[si].w + __shfl_xor(sum[si].w, 32);
            const int s = 2 * wv_ + si;
            if (sub == 0) {
                *reinterpret_cast<float4*>(&catl[s][4 * d4]) = orgv[si];
            } else {
                *reinterpret_cast<float4*>(&catl[s][D + 4 * d4]) =
                    make_float4(tot.x * 0.0625f, tot.y * 0.0625f,
                                tot.z * 0.0625f, tot.w * 0.0625f);
            }
        }
    }

    // ---- Wo loads (coalesced), then swizzled LDS writes ----
    float4 wv[8];
    #pragma unroll
    for (int i = 0; i < 8; ++i)
        wv[i] = reinterpret_cast<const float4*>(Wo)[t + i * 256];
    #pragma unroll
    for (int i = 0; i < 8; ++i) {         // wol[c][k4 ^ (c&7)] quad-swizzle
        const int idx = t + i * 256, c = idx >> 5, k4 = idx & 31;
        *reinterpret_cast<float4*>(&wol[c][((k4 & 24) | ((k4 ^ c) & 7)) << 2]) = wv[i];
    }

    const int j0  = t & 63;               // W2 rows j0, j0+64
    const int sg  = t >> 6;               // seed group
    const int sA  = sg * 2, sB = sA + 1;
    const int swz = j0 & 7;
    float acc00 = 0.f, acc01 = 0.f, acc10 = 0.f, acc11 = 0.f;

    // ---- 8 W2 panels, double-buffered; prefetch p+1 under compute(p) ----
    for (int p = 0; p < 8; ++p) {
        const int cur = p & 1;
        #pragma unroll
        for (int i = 0; i < 4; ++i) {     // w2l[row][c4 ^ (row&7)]
            const int idx = t + i * 256, row = idx >> 3, c4 = idx & 7;
            *reinterpret_cast<float4*>(&w2l[cur][row][(c4 ^ (row & 7)) << 2]) = pv[i];
        }
        __syncthreads();
        if (p < 7) {
            #pragma unroll
            for (int i = 0; i < 4; ++i) {
                const int idx = t + i * 256, row = idx >> 3, c4 = idx & 7;
                pv[i] = *reinterpret_cast<const float4*>(
                    W2 + (size_t)row * (2 * D) + (p + 1) * KP + c4 * 4);
            }
        }
        #pragma unroll
        for (int k4 = 0; k4 < 8; ++k4) {
            const float4 wA = *reinterpret_cast<const float4*>(&w2l[cur][j0][(k4 ^ swz) << 2]);
            const float4 wB = *reinterpret_cast<const float4*>(&w2l[cur][j0 + 64][(k4 ^ swz) << 2]);
            const float4 cA = *reinterpret_cast<const float4*>(&catl[sA][p * KP + k4 * 4]);
            const float4 cB = *reinterpret_cast<const float4*>(&catl[sB][p * KP + k4 * 4]);
            acc00 = fmaf(wA.x, cA.x, acc00); acc00 = fmaf(wA.y, cA.y, acc00);
            acc00 = fmaf(wA.z, cA.z, acc00); acc00 = fmaf(wA.w, cA.w, acc00);
            acc01 = fmaf(wA.x, cB.x, acc01); acc01 = fmaf(wA.y, cB.y, acc01);
            acc01 = fmaf(wA.z, cB.z, acc01); acc01 = fmaf(wA.w, cB.w, acc01);
            acc10 = fmaf(wB.x, cA.x, acc10); acc10 = fmaf(wB.y, cA.y, acc10);
            acc10 = fmaf(wB.z, cA.z, acc10); acc10 = fmaf(wB.w, cA.w, acc10);
            acc11 = fmaf(wB.x, cB.x, acc11); acc11 = fmaf(wB.y, cB.y, acc11);
            acc11 = fmaf(wB.z, cB.z, acc11); acc11 = fmaf(wB.w, cB.w, acc11);
        }
        __syncthreads();
    }

    // keep accs live across reps (blocks cross-rep CSE of the whole MLP)
    asm volatile("" : "+v"(acc00), "+v"(acc01), "+v"(acc10), "+v"(acc11));

    // ---- relu -> hl ----
    hl[sA][j0]      = acc00 > 0.f ? acc00 : 0.f;
    hl[sB][j0]      = acc01 > 0.f ? acc01 : 0.f;
    hl[sA][j0 + 64] = acc10 > 0.f ? acc10 : 0.f;
    hl[sB][j0 + 64] = acc11 > 0.f ? acc11 : 0.f;
    __syncthreads();

    // ---- output layer + softmax: lane = class; wave sg does seeds sA,sB ----
    {
        const int c = t & 63;
        const int cswz = c & 7;
        float a0 = 0.f, a1 = 0.f;
        #pragma unroll
        for (int k4 = 0; k4 < 32; ++k4) {
            const float4 w = *reinterpret_cast<const float4*>(
                &wol[c][((k4 & 24) | ((k4 ^ cswz) & 7)) << 2]);
            const float4 h0 = *reinterpret_cast<const float4*>(&hl[sA][k4 * 4]);
            const float4 h1 = *reinterpret_cast<const float4*>(&hl[sB][k4 * 4]);
            a0 = fmaf(w.x, h0.x, a0); a0 = fmaf(w.y, h0.y, a0);
            a0 = fmaf(w.z, h0.z, a0); a0 = fmaf(w.w, h0.w, a0);
            a1 = fmaf(w.x, h1.x, a1); a1 = fmaf(w.y, h1.y, a1);
            a1 = fmaf(w.z, h1.z, a1); a1 = fmaf(w.w, h1.w, a1);
        }
        float m0 = a0, m1 = a1;
        #pragma unroll
        for (int off = 32; off >= 1; off >>= 1) {
            m0 = fmaxf(m0, __shfl_xor(m0, off));
            m1 = fmaxf(m1, __shfl_xor(m1, off));
        }
        const float e0 = __expf(a0 - m0), e1 = __expf(a1 - m1);
        float z0 = e0, z1 = e1;
        #pragma unroll
        for (int off = 32; off >= 1; off >>= 1) {
            z0 += __shfl_xor(z0, off);
            z1 += __shfl_xor(z1, off);
        }
        out[(size_t)(s0 + sA) * O + c] = e0 / z0;
        out[(size_t)(s0 + sB) * O + c] = e1 / z1;
    }
    __syncthreads();   // rep N+1's catl/wol writes must not race output reads
    }                  // rep loop
}

extern "C" void kernel_launch(void* const* d_in, const int* in_sizes, int n_in,
                              void* d_out, int out_size, void* d_ws, size_t ws_size,
                              hipStream_t stream) {
    const int*   nodes         = (const int*)d_in[0];
    const int*   neighbors_1   = (const int*)d_in[1];
    const float* node_features = (const float*)d_in[3];
    const float* W2            = (const float*)d_in[5];
    const float* Wo            = (const float*)d_in[6];
    float*       out           = (float*)d_out;

    sage_fused<<<NB / SPB, 256, 0, stream>>>(
        nodes, neighbors_1, node_features, W2, Wo, out);
}